// Round 14
// baseline (2864.734 us; speedup 1.0000x reference)
//
#include <hip/hip_runtime.h>
#include <hip/hip_bf16.h>
#include <math.h>

#define SEQ   32
#define BATCH 1024
#define NN    19
#define HH    128
#define NB    4            /* batch elements per block */
#define MR    (NB*NN)      /* 76 rows per block */
#define SAS   264          /* sA row stride (bf16): 528 B = 16B-aligned, 4-bank shift */
#define H0S   128          /* h0 row stride (bf16) */
#define H1S   132          /* h1 row stride (f32): 528 B, 16B-aligned */
#define UBS   128          /* ub row stride (bf16) */
#define NBLK  (BATCH/NB)   /* 256 blocks, 1 per CU */
#define NT    1024         /* 16 waves, 4 per SIMD */
#define UST_S 40           /* Ust col stride (elems): 80 B = 16B-aligned, 20-bank shift */

#define OFF_G0 0
#define OFF_C0 122880
#define OFF_G1 184320
#define OFF_C1 380928
#define WTOT   479232      /* total weight elems (bf16) */

/* LDS map:
   h0   @      0  76*128*2 = 19456
   h1   @  19456  76*132*4 = 40128   (end  59584)
   sA   @  59584  80*264*2 = 42240   (end 101824; rows 76-79 stay zero)
   ub   @ 101824  76*128*2 = 19456   (end 121280)
   sbf  @ 121280  2*9*512*2= 18432   (end 139712; Tblk MFMA A-frags)
   Ust  @ 139712 16*16*40*2= 20480   (end 160192; per-wave mixing scratch)
   xp   @ 160192  76*4     =   304   (end 160496)  */
#define OFF_H0  0
#define OFF_H1  19456
#define OFF_SA  59584
#define OFF_UB  101824
#define OFF_SBF 121280
#define OFF_UST 139712
#define OFF_XP  160192
#define LDS_BYTES 160496

// Weights + Chebyshev block-diag fragments in device-global (L2-resident).
__device__ unsigned short g_wall[WTOT];
/* g_sbf: MFMA A-fragments of Tblk1 = blockdiag(S) (frags 0..8) and
   Tblk2 = blockdiag(2S^2-I) (frags 9..17), fragment-major [frag][lane][8],
   frag order grouped by kt: kt0:(mt 0,1,2) kt1:(mt 1,2,3,4) kt2:(mt 3,4). */
__device__ unsigned short g_sbf[2*9*512];

typedef __attribute__((ext_vector_type(8))) short  bf16x8;
typedef __attribute__((ext_vector_type(4))) short  bf16x4;
typedef __attribute__((ext_vector_type(4))) float  f32x4;

__device__ __forceinline__ unsigned short f2bf(float v) {
    __hip_bfloat16 b = __float2bfloat16(v);
    return *reinterpret_cast<unsigned short*>(&b);
}
__device__ __forceinline__ float bf2f(unsigned short u) {
    unsigned int x = ((unsigned int)u) << 16;
    return __uint_as_float(x);
}
__device__ __forceinline__ float hload(const unsigned short* p) { return bf2f(*p); }
__device__ __forceinline__ float hload(const float* p)          { return *p; }
__device__ __forceinline__ void  hstore(unsigned short* p, float v) { *p = f2bf(v); }
__device__ __forceinline__ void  hstore(float* p, float v)          { *p = v; }

// ---------------------------------------------------------------------------
// Setup 1: weight reorder/transpose into g_wall.
// Layer-0 (l0=1) K layout is [h(0..127) | x(128) | pad] so staging vectorizes.
// ---------------------------------------------------------------------------
__global__ __launch_bounds__(256) void wconv_kernel(
    const float* __restrict__ W, int F, int O, int KP, int off, int l0)
{
    int idx = blockIdx.x*256 + threadIdx.x;
    int total = 3*O*KP;
    if (idx >= total) return;
    int j   = idx / (O*KP);
    int r   = idx - j*(O*KP);
    int col = r / KP;
    int k   = r - col*KP;
    int src;
    if (l0) src = (k < HH) ? k+1 : ((k == HH) ? 0 : -1);
    else    src = (k < F) ? k : -1;
    float v = (src >= 0) ? W[(size_t)(j*F + src)*O + col] : 0.f;
    g_wall[off + idx] = f2bf(v);
}

// ---------------------------------------------------------------------------
// Setup 2: Tblk fragments (80x96 block-diag, zero-padded).
// A-frag layout (mfma_16x16x32): lane l, elem e ->
//   Tblk[fmt*16 + (l&15)][fkt*32 + (l>>4)*8 + e]
// ---------------------------------------------------------------------------
__global__ __launch_bounds__(256) void sbf_kernel(const float* __restrict__ S)
{
    __shared__ float sS[NN*NN], sS2[NN*NN];
    int tid = threadIdx.x;
    for (int i = tid; i < NN*NN; i += 256) sS[i] = S[i];
    __syncthreads();
    for (int i = tid; i < NN*NN; i += 256) {
        int m = i/NN, n = i - m*NN;
        float a = 0.f;
        for (int k = 0; k < NN; ++k) a += sS[m*NN+k]*sS[k*NN+n];
        sS2[i] = a;
    }
    __syncthreads();
    const int fmt[9] = {0,1,2, 1,2,3,4, 3,4};
    const int fkt[9] = {0,0,0, 1,1,1,1, 2,2};
    for (int idx = tid; idx < 2*9*512; idx += 256) {
        int mat = idx / 4608;
        int rem = idx - mat*4608;
        int i   = rem >> 9;
        int l   = (rem >> 3) & 63;
        int e   = rem & 7;
        int r   = fmt[i]*16 + (l & 15);
        int k   = fkt[i]*32 + (l >> 4)*8 + e;
        float v = 0.f;
        if (r < MR) {
            int b = r / NN, m = r - b*NN;
            int k0 = b*NN;
            if (k >= k0 && k < k0 + NN) {
                int n = k - k0;
                v = (mat == 0) ? sS[m*NN+n]
                               : (2.f*sS2[m*NN+n] - ((m==n)?1.f:0.f));
            }
        }
        g_sbf[idx] = f2bf(v);
    }
}

// ---------------------------------------------------------------------------
// One gconv phase, NTC=1 per wave (16 cols):
//   K-loop SPLIT PER j-SEGMENT (one weight stream in flight at a time;
//   in-loop arch-reg demand ~35 vs the fused loop's ~100 — the fused
//   3-stream form spilled every round r5-r13).  acc[3][5] persists across
//   segments (AGPR-resident, r9-proven).  af re-read per segment (LDS).
//   Then Y = acc[0] + Tblk1@acc[1] + Tblk2@acc[2] via per-wave Ust scratch.
// GATE epilogue: r -> sA cols [XW,XW+128), u -> ub.  CAND: h update.
// ---------------------------------------------------------------------------
template<int KS, int OC, bool GATE, int XW, typename HT, int HSTR>
__device__ __forceinline__ void gconv_phase(
    const unsigned short* __restrict__ BT, const float* __restrict__ bias,
    HT* __restrict__ hL,
    unsigned short* __restrict__ sA, unsigned short* __restrict__ ub,
    const unsigned short* __restrict__ sbf, unsigned short* __restrict__ Ust,
    int lane, int w)
{
    constexpr int KP = KS*32;
    const int r16 = lane & 15, quad = lane >> 4;
    const int sgo = w*16;
    const bool act = (sgo < OC);     /* wave-uniform; inactive only for cand */

    constexpr int ktCnt[3]   = {3,4,2};
    constexpr int ktMT[3][4] = {{0,1,2,0},{1,2,3,4},{3,4,0,0}};
    constexpr int ktF0[3]    = {0,3,7};

    f32x4 acc[3][5];
    if (act) {
        #pragma unroll
        for (int j = 0; j < 3; ++j)
            #pragma unroll
            for (int mt = 0; mt < 5; ++mt) acc[j][mt] = (f32x4)0.f;

        /* three sequential single-stream K-loops, depth-2 ring each */
        #pragma unroll
        for (int j = 0; j < 3; ++j) {
            const unsigned short* wp =
                BT + (size_t)(j*OC + sgo + r16)*KP + quad*8;
            bf16x8 rg0 = *(const bf16x8*)(wp);
            bf16x8 rg1 = (KS > 1) ? *(const bf16x8*)(wp + 32) : rg0;
            #pragma unroll
            for (int ks = 0; ks < KS; ++ks) {
                bf16x8 cur = (ks & 1) ? rg1 : rg0;
                if (ks + 2 < KS) {
                    if (ks & 1) rg1 = *(const bf16x8*)(wp + (ks + 2)*32);
                    else        rg0 = *(const bf16x8*)(wp + (ks + 2)*32);
                }
                #pragma unroll
                for (int mt = 0; mt < 5; ++mt) {
                    bf16x8 af = *(const bf16x8*)
                        &sA[(mt*16 + r16)*SAS + ks*32 + quad*8];
                    acc[j][mt] = __builtin_amdgcn_mfma_f32_16x16x32_bf16(
                        af, cur, acc[j][mt], 0, 0, 0);
                }
            }
        }

        /* ---- output-side mixing: acc[0] += Tblk_jj @ acc[jj] ----
           Ust[col][r]: col = wave-local out col (r16), r = U row in the kt
           tile.  C-layout reg-quad is contiguous in r -> b64 writes.  Rows
           16..31 at kt=2 hold stale mt3 data (always finite, staged this
           same phase) multiplying zero Tblk cols -> no zero-fill needed. */
        #pragma unroll
        for (int jj = 1; jj <= 2; ++jj) {
            #pragma unroll
            for (int kt = 0; kt < 3; ++kt) {
                #pragma unroll
                for (int mtk = 0; mtk < 2; ++mtk) {
                    if (kt*2 + mtk < 5) {
                        bf16x4 pv;
                        pv[0] = (short)f2bf(acc[jj][kt*2+mtk][0]);
                        pv[1] = (short)f2bf(acc[jj][kt*2+mtk][1]);
                        pv[2] = (short)f2bf(acc[jj][kt*2+mtk][2]);
                        pv[3] = (short)f2bf(acc[jj][kt*2+mtk][3]);
                        *(bf16x4*)&Ust[r16*UST_S + mtk*16 + quad*4] = pv;
                    }
                }
                bf16x8 Bf = *(const bf16x8*)&Ust[r16*UST_S + quad*8];
                #pragma unroll
                for (int q = 0; q < ktCnt[kt]; ++q) {
                    const int mt = ktMT[kt][q];
                    bf16x8 af = *(const bf16x8*)
                        &sbf[((jj-1)*9 + ktF0[kt] + q)*512 + lane*8];
                    acc[0][mt] = __builtin_amdgcn_mfma_f32_16x16x32_bf16(
                        af, Bf, acc[0][mt], 0, 0, 0);
                }
            }
        }
    }

    float bv = act ? bias[sgo + r16] : 0.f;

    if (GATE) __syncthreads();   /* all sA reads done before epilogue rewrites */

    if (act) {
        #pragma unroll
        for (int mt = 0; mt < 5; ++mt)
            #pragma unroll
            for (int reg = 0; reg < 4; ++reg) {
                int gm = mt*16 + quad*4 + reg;
                if (gm < MR) {
                    int o = sgo + r16;
                    float v = acc[0][mt][reg] + bv;
                    if (GATE) {
                        float sg_ = 1.f/(1.f + __expf(-v));
                        if (o < HH)
                            sA[gm*SAS + XW + o] =
                                f2bf(sg_ * hload(&hL[gm*HSTR + o]));
                        else
                            ub[gm*UBS + (o - HH)] = f2bf(sg_);
                    } else {
                        float c  = 2.f/(1.f + __expf(-2.f*v)) - 1.f;
                        float u  = bf2f(ub[gm*UBS + o]);
                        float ho = hload(&hL[gm*HSTR + o]);
                        hstore(&hL[gm*HSTR + o], u*ho + (1.f - u)*c);
                    }
                }
            }
    }
}

// ---------------------------------------------------------------------------
// Persistent kernel: 256 blocks x 1024 threads (16 waves, 4/SIMD).
// amdgpu_waves_per_eu(4,4): exactly 4 waves/EU (LDS caps us there anyway).
// ---------------------------------------------------------------------------
__global__ __launch_bounds__(NT)
__attribute__((amdgpu_waves_per_eu(4, 4)))
void dcgru_persistent(
    const float* __restrict__ ihs,
    const float* __restrict__ bg0, const float* __restrict__ bc0,
    const float* __restrict__ bg1, const float* __restrict__ bc1,
    const float* __restrict__ Wp, const float* __restrict__ bp,
    float* __restrict__ out)
{
    extern __shared__ char smem[];
    unsigned short* h0  = (unsigned short*)(smem + OFF_H0);
    float*          h1  = (float*)(smem + OFF_H1);
    unsigned short* sA  = (unsigned short*)(smem + OFF_SA);
    unsigned short* ub  = (unsigned short*)(smem + OFF_UB);
    unsigned short* sbf = (unsigned short*)(smem + OFF_SBF);
    float*       xprev  = (float*)(smem + OFF_XP);

    const int tid  = threadIdx.x;
    const int lane = tid & 63;
    const int w    = tid >> 6;          /* 0..15 */
    const int bb   = blockIdx.x * NB;
    unsigned short* Ust = (unsigned short*)(smem + OFF_UST) + w*(16*UST_S);

    const unsigned short* BTg0 = g_wall + OFF_G0;
    const unsigned short* BTc0 = g_wall + OFF_C0;
    const unsigned short* BTg1 = g_wall + OFF_G1;
    const unsigned short* BTc1 = g_wall + OFF_C1;

    for (int i = tid; i < MR*HH; i += NT) {
        h0[i] = f2bf(ihs[(size_t)bb*2432 + i]);
        h1[(i >> 7)*H1S + (i & 127)] = ihs[(size_t)(BATCH + bb)*2432 + i];
    }
    for (int i = tid; i < MR; i += NT) xprev[i] = 0.f;
    /* zero sA fully (pad rows 76-79 + pad cols stay zero) and Ust (so any
       stale read is finite) */
    for (int i = tid; i < 80*SAS/8; i += NT) ((bf16x8*)sA)[i] = (bf16x8)(short)0;
    for (int i = tid; i < 16*16*UST_S/8; i += NT)
        ((bf16x8*)(smem + OFF_UST))[i] = (bf16x8)(short)0;
    /* Tblk fragments -> LDS (18 KB, once) */
    for (int i = tid; i < 2*9*512/8; i += NT)
        ((bf16x8*)sbf)[i] = ((const bf16x8*)g_sbf)[i];
    const float wp0 = Wp[lane], wp1 = Wp[64 + lane], bpv = bp[0];
    __syncthreads();

    for (int t = 0; t < SEQ; ++t) {
        // ---- stage layer 0: sA = [h0 | x | 0-pad]  (K = 160) ----
        for (int i = tid; i < MR*16; i += NT) {
            int row = i >> 4, ch = i & 15;
            *(bf16x8*)&sA[row*SAS + ch*8] =
                *(const bf16x8*)&h0[row*H0S + ch*8];
        }
        for (int i = tid; i < MR*4; i += NT) {
            int row = i >> 2, ch = i & 3;
            bf16x8 v = (bf16x8)(short)0;
            if (ch == 0) v[0] = (short)f2bf(xprev[row]);
            *(bf16x8*)&sA[row*SAS + HH + ch*8] = v;
        }
        __syncthreads();
        gconv_phase<5,256,true ,0,unsigned short,H0S>(BTg0, bg0, h0, sA, ub, sbf, Ust, lane, w);
        __syncthreads();
        /* sA now [r*h0 | x | 0] */
        gconv_phase<5,128,false,0,unsigned short,H0S>(BTc0, bc0, h0, sA, ub, sbf, Ust, lane, w);
        __syncthreads();

        // ---- stage layer 1: sA = [h0 | h1]  (K = 256) ----
        for (int i = tid; i < MR*16; i += NT) {
            int row = i >> 4, ch = i & 15;
            *(bf16x8*)&sA[row*SAS + ch*8] =
                *(const bf16x8*)&h0[row*H0S + ch*8];
        }
        for (int i = tid; i < MR*16; i += NT) {
            int row = i >> 4, ch = i & 15;
            const float* hp = &h1[row*H1S + ch*8];
            f32x4 x0 = *(const f32x4*)hp;
            f32x4 x1 = *(const f32x4*)(hp + 4);
            bf16x8 v;
            v[0] = (short)f2bf(x0[0]); v[1] = (short)f2bf(x0[1]);
            v[2] = (short)f2bf(x0[2]); v[3] = (short)f2bf(x0[3]);
            v[4] = (short)f2bf(x1[0]); v[5] = (short)f2bf(x1[1]);
            v[6] = (short)f2bf(x1[2]); v[7] = (short)f2bf(x1[3]);
            *(bf16x8*)&sA[row*SAS + HH + ch*8] = v;
        }
        __syncthreads();
        gconv_phase<8,256,true ,HH,float,H1S>(BTg1, bg1, h1, sA, ub, sbf, Ust, lane, w);
        __syncthreads();
        /* sA now [h0 | r*h1] */
        gconv_phase<8,128,false,HH,float,H1S>(BTc1, bc1, h1, sA, ub, sbf, Ust, lane, w);
        __syncthreads();

        // ---- projection: wave w -> batch w>>2, <=5 nodes each ----
        {
            int b  = w >> 2;
            int n0 = (w & 3) * 5;
            int n1 = n0 + 5; if (n1 > NN) n1 = NN;
            for (int n = n0; n < n1; ++n) {
                int row = b*NN + n;
                float s = h1[row*H1S + lane]*wp0 + h1[row*H1S + 64 + lane]*wp1;
                #pragma unroll
                for (int off = 32; off; off >>= 1) s += __shfl_down(s, off, 64);
                if (lane == 0) {
                    float v = s + bpv;
                    out[((size_t)t*BATCH + bb + b)*NN + n] = v;
                    xprev[row] = v;
                }
            }
        }
        __syncthreads();
    }
}

// ---------------------------------------------------------------------------
extern "C" void kernel_launch(void* const* d_in, const int* in_sizes, int n_in,
                              void* d_out, int out_size, void* d_ws, size_t ws_size,
                              hipStream_t stream) {
    const float* ihs = (const float*)d_in[1];
    const float* S   = (const float*)d_in[2];
    const float* Wg0 = (const float*)d_in[3];
    const float* bg0 = (const float*)d_in[4];
    const float* Wc0 = (const float*)d_in[5];
    const float* bc0 = (const float*)d_in[6];
    const float* Wg1 = (const float*)d_in[7];
    const float* bg1 = (const float*)d_in[8];
    const float* Wc1 = (const float*)d_in[9];
    const float* bc1 = (const float*)d_in[10];
    const float* Wp  = (const float*)d_in[11];
    const float* bp  = (const float*)d_in[12];
    float* out = (float*)d_out;

    sbf_kernel<<<1, 256, 0, stream>>>(S);
    wconv_kernel<<<(3*256*160+255)/256, 256, 0, stream>>>(Wg0, 129, 256, 160, OFF_G0, 1);
    wconv_kernel<<<(3*128*160+255)/256, 256, 0, stream>>>(Wc0, 129, 128, 160, OFF_C0, 1);
    wconv_kernel<<<(3*256*256+255)/256, 256, 0, stream>>>(Wg1, 256, 256, 256, OFF_G1, 0);
    wconv_kernel<<<(3*128*256+255)/256, 256, 0, stream>>>(Wc1, 256, 128, 256, OFF_C1, 0);

    hipFuncSetAttribute((const void*)dcgru_persistent,
                        hipFuncAttributeMaxDynamicSharedMemorySize, LDS_BYTES);

    dcgru_persistent<<<NBLK, NT, LDS_BYTES, stream>>>(
        ihs, bg0, bc0, bg1, bc1, Wp, bp, out);
}

// Round 15
// 2801.183 us; speedup vs baseline: 1.0227x; 1.0227x over previous
//
#include <hip/hip_runtime.h>
#include <hip/hip_bf16.h>
#include <math.h>

#define SEQ   32
#define BATCH 1024
#define NN    19
#define HH    128
#define NB    4            /* batch elements per block */
#define MR    (NB*NN)      /* 76 rows per block */
#define SAS   264          /* sA row stride (bf16): 528 B = 16B-aligned, 4-bank shift */
#define H0S   128          /* h0 row stride (bf16) */
#define H1S   132          /* h1 row stride (f32): 528 B, 16B-aligned */
#define UBS   128          /* ub row stride (bf16) */
#define NBLK  (BATCH/NB)   /* 256 blocks, 1 per CU */
#define NT    1024         /* 16 waves, 4 per SIMD */
#define UST_S 40           /* Ust col stride (elems): 80 B = 16B-aligned, 20-bank shift */

/* weight wall offsets (layer-0 KP=128 now: K=129 split into K-loop(128) +
   rank-1 x column in f32 g_wx) */
#define OFF_G0 0
#define OFF_C0 98304       /* 3*256*128 */
#define OFF_G1 147456      /* +3*128*128 */
#define OFF_C1 344064      /* +3*256*256 */
#define WTOT   442368      /* +3*128*256 */

/* LDS map (r9):
   h0   @      0  76*128*2 = 19456
   h1   @  19456  76*132*4 = 40128   (end  59584)
   sA   @  59584  80*264*2 = 42240   (end 101824; rows 76-79 stay zero;
                                      cols 0-127 = PERSISTENT h0 copy)
   ub   @ 101824  76*128*2 = 19456   (end 121280)
   sbf  @ 121280  2*9*512*2= 18432   (end 139712; Tblk MFMA A-frags)
   Ust  @ 139712 16*16*40*2= 20480   (end 160192; per-wave mixing scratch)
   xp   @ 160192  76*4     =   304   (end 160496)  */
#define OFF_H0  0
#define OFF_H1  19456
#define OFF_SA  59584
#define OFF_UB  101824
#define OFF_SBF 121280
#define OFF_UST 139712
#define OFF_XP  160192
#define LDS_BYTES 160496

// Weights + Chebyshev block-diag fragments in device-global (L2-resident).
__device__ unsigned short g_wall[WTOT];
/* x-column weights for layer-0, f32: [gate0: 3*256][cand0: 3*128] */
__device__ float g_wx[3*256 + 3*128];
/* g_sbf: MFMA A-fragments of Tblk1 = blockdiag(S) (frags 0..8) and
   Tblk2 = blockdiag(2S^2-I) (frags 9..17), fragment-major [frag][lane][8],
   frag order grouped by kt: kt0:(mt 0,1,2) kt1:(mt 1,2,3,4) kt2:(mt 3,4). */
__device__ unsigned short g_sbf[2*9*512];

typedef __attribute__((ext_vector_type(8))) short  bf16x8;
typedef __attribute__((ext_vector_type(4))) short  bf16x4;
typedef __attribute__((ext_vector_type(4))) float  f32x4;

__device__ __forceinline__ unsigned short f2bf(float v) {
    __hip_bfloat16 b = __float2bfloat16(v);
    return *reinterpret_cast<unsigned short*>(&b);
}
__device__ __forceinline__ float bf2f(unsigned short u) {
    unsigned int x = ((unsigned int)u) << 16;
    return __uint_as_float(x);
}
__device__ __forceinline__ float hload(const unsigned short* p) { return bf2f(*p); }
__device__ __forceinline__ float hload(const float* p)          { return *p; }
__device__ __forceinline__ void  hstore(unsigned short* p, float v) { *p = f2bf(v); }
__device__ __forceinline__ void  hstore(float* p, float v)          { *p = v; }

// ---------------------------------------------------------------------------
// Setup 1: weight reorder/transpose into g_wall.
// Layer-0 (l0=1): KP=128, K layout = h(0..127) only (x handled via g_wx).
// ---------------------------------------------------------------------------
__global__ __launch_bounds__(256) void wconv_kernel(
    const float* __restrict__ W, int F, int O, int KP, int off, int l0)
{
    int idx = blockIdx.x*256 + threadIdx.x;
    int total = 3*O*KP;
    if (idx >= total) return;
    int j   = idx / (O*KP);
    int r   = idx - j*(O*KP);
    int col = r / KP;
    int k   = r - col*KP;
    int src;
    if (l0) src = k + 1;                 /* h features are rows 1..128 */
    else    src = (k < F) ? k : -1;
    float v = (src >= 0 && src < F) ? W[(size_t)(j*F + src)*O + col] : 0.f;
    g_wall[off + idx] = f2bf(v);
}

// ---------------------------------------------------------------------------
// Setup 1b: x-column weights (feature row 0 of layer-0 W matrices), f32.
// ---------------------------------------------------------------------------
__global__ __launch_bounds__(256) void wx_kernel(
    const float* __restrict__ Wg0, const float* __restrict__ Wc0)
{
    int i = blockIdx.x*256 + threadIdx.x;
    if (i < 3*256) {
        int j = i >> 8, col = i & 255;
        g_wx[i] = Wg0[(size_t)(j*129)*256 + col];
    } else if (i < 3*256 + 3*128) {
        int r = i - 3*256;
        int j = r >> 7, col = r & 127;
        g_wx[i] = Wc0[(size_t)(j*129)*128 + col];
    }
}

// ---------------------------------------------------------------------------
// Setup 2: Tblk fragments (80x96 block-diag, zero-padded).
// A-frag layout (mfma_16x16x32): lane l, elem e ->
//   Tblk[fmt*16 + (l&15)][fkt*32 + (l>>4)*8 + e]
// ---------------------------------------------------------------------------
__global__ __launch_bounds__(256) void sbf_kernel(const float* __restrict__ S)
{
    __shared__ float sS[NN*NN], sS2[NN*NN];
    int tid = threadIdx.x;
    for (int i = tid; i < NN*NN; i += 256) sS[i] = S[i];
    __syncthreads();
    for (int i = tid; i < NN*NN; i += 256) {
        int m = i/NN, n = i - m*NN;
        float a = 0.f;
        for (int k = 0; k < NN; ++k) a += sS[m*NN+k]*sS[k*NN+n];
        sS2[i] = a;
    }
    __syncthreads();
    const int fmt[9] = {0,1,2, 1,2,3,4, 3,4};
    const int fkt[9] = {0,0,0, 1,1,1,1, 2,2};
    for (int idx = tid; idx < 2*9*512; idx += 256) {
        int mat = idx / 4608;
        int rem = idx - mat*4608;
        int i   = rem >> 9;
        int l   = (rem >> 3) & 63;
        int e   = rem & 7;
        int r   = fmt[i]*16 + (l & 15);
        int k   = fkt[i]*32 + (l >> 4)*8 + e;
        float v = 0.f;
        if (r < MR) {
            int b = r / NN, m = r - b*NN;
            int k0 = b*NN;
            if (k >= k0 && k < k0 + NN) {
                int n = k - k0;
                v = (mat == 0) ? sS[m*NN+n]
                               : (2.f*sS2[m*NN+n] - ((m==n)?1.f:0.f));
            }
        }
        g_sbf[idx] = f2bf(v);
    }
}

// ---------------------------------------------------------------------------
// One gconv phase, NTC=1 per wave (16 cols), flat fused structure (r9):
//   acc[j] = X @ Wj  (fused 3-segment K-loop, depth-2 weight ring)
//   + X1: rank-1 x-column term acc[j] += xprev[row]*Wx[j][col] (f32, exact)
//   Y = acc[0] + Tblk1@acc[1] + Tblk2@acc[2] via per-wave Ust LDS scratch.
// GATE epilogue: r -> sA cols [XW,XW+128), u -> ub.
// CAND epilogue: h update; WS additionally writes h0new into sA cols 0-127
//   (sA is the persistent h0 home — stage0 is gone).
// ---------------------------------------------------------------------------
template<int KS, int OC, bool GATE, int XW, bool X1, bool WS,
         typename HT, int HSTR>
__device__ __forceinline__ void gconv_phase(
    const unsigned short* __restrict__ BT, const float* __restrict__ bias,
    HT* __restrict__ hL,
    unsigned short* __restrict__ sA, unsigned short* __restrict__ ub,
    const unsigned short* __restrict__ sbf, unsigned short* __restrict__ Ust,
    const float* __restrict__ wx, const float* __restrict__ xprev,
    int lane, int w)
{
    constexpr int KP = KS*32;
    const int r16 = lane & 15, quad = lane >> 4;
    const int sgo = w*16;
    const bool act = (sgo < OC);     /* wave-uniform; inactive only for cand */

    constexpr int ktCnt[3]   = {3,4,2};
    constexpr int ktMT[3][4] = {{0,1,2,0},{1,2,3,4},{3,4,0,0}};
    constexpr int ktF0[3]    = {0,3,7};

    f32x4 acc[3][5];
    if (act) {
        const unsigned short* wb[3];
        #pragma unroll
        for (int j = 0; j < 3; ++j)
            wb[j] = BT + (size_t)(j*OC + sgo + r16)*KP + quad*8;

        #pragma unroll
        for (int j = 0; j < 3; ++j)
            #pragma unroll
            for (int mt = 0; mt < 5; ++mt) acc[j][mt] = (f32x4)0.f;

        /* fused K-loop, depth-2 weight ring (af read once per j-triple) */
        bf16x8 ring[2][3];
        #pragma unroll
        for (int j = 0; j < 3; ++j) {
            ring[0][j] = *(const bf16x8*)(wb[j]);
            if (KS > 1) ring[1][j] = *(const bf16x8*)(wb[j] + 32);
        }
        #pragma unroll
        for (int ks = 0; ks < KS; ++ks) {
            bf16x8 bcur[3];
            #pragma unroll
            for (int j = 0; j < 3; ++j) bcur[j] = ring[ks & 1][j];
            if (ks + 2 < KS) {
                #pragma unroll
                for (int j = 0; j < 3; ++j)
                    ring[ks & 1][j] = *(const bf16x8*)(wb[j] + (ks + 2)*32);
            }
            #pragma unroll
            for (int mt = 0; mt < 5; ++mt) {
                bf16x8 af = *(const bf16x8*)&sA[(mt*16 + r16)*SAS + ks*32 + quad*8];
                #pragma unroll
                for (int j = 0; j < 3; ++j)
                    acc[j][mt] = __builtin_amdgcn_mfma_f32_16x16x32_bf16(
                        af, bcur[j], acc[j][mt], 0, 0, 0);
            }
        }

        /* rank-1 x-column (layer-0): exact f32, added BEFORE mixing so the
           Chebyshev diffusion applies to it too. */
        if (X1) {
            float wxv[3];
            #pragma unroll
            for (int j = 0; j < 3; ++j) wxv[j] = wx[j*OC + sgo + r16];
            #pragma unroll
            for (int mt = 0; mt < 5; ++mt)
                #pragma unroll
                for (int reg = 0; reg < 4; ++reg) {
                    int gm = mt*16 + quad*4 + reg;
                    float xv = (gm < MR) ? xprev[gm] : 0.f;
                    #pragma unroll
                    for (int j = 0; j < 3; ++j)
                        acc[j][mt][reg] += xv * wxv[j];
                }
        }

        /* ---- output-side mixing: acc[0] += Tblk_jj @ acc[jj] ----
           Ust[col][r]: col = wave-local out col (r16), r = U row in the kt
           tile.  C-layout reg-quad is contiguous in r -> b64 writes.  Rows
           16..31 at kt=2 hold stale mt3 data (always finite, staged this
           same phase) multiplying zero Tblk cols -> no zero-fill needed. */
        #pragma unroll
        for (int jj = 1; jj <= 2; ++jj) {
            #pragma unroll
            for (int kt = 0; kt < 3; ++kt) {
                #pragma unroll
                for (int mtk = 0; mtk < 2; ++mtk) {
                    if (kt*2 + mtk < 5) {
                        bf16x4 pv;
                        pv[0] = (short)f2bf(acc[jj][kt*2+mtk][0]);
                        pv[1] = (short)f2bf(acc[jj][kt*2+mtk][1]);
                        pv[2] = (short)f2bf(acc[jj][kt*2+mtk][2]);
                        pv[3] = (short)f2bf(acc[jj][kt*2+mtk][3]);
                        *(bf16x4*)&Ust[r16*UST_S + mtk*16 + quad*4] = pv;
                    }
                }
                bf16x8 Bf = *(const bf16x8*)&Ust[r16*UST_S + quad*8];
                #pragma unroll
                for (int q = 0; q < ktCnt[kt]; ++q) {
                    const int mt = ktMT[kt][q];
                    bf16x8 af = *(const bf16x8*)
                        &sbf[((jj-1)*9 + ktF0[kt] + q)*512 + lane*8];
                    acc[0][mt] = __builtin_amdgcn_mfma_f32_16x16x32_bf16(
                        af, Bf, acc[0][mt], 0, 0, 0);
                }
            }
        }
    }

    float bv = act ? bias[sgo + r16] : 0.f;

    /* all waves' sA reads must complete before GATE's r-write or WS's
       h0new-write rewrites sA */
    if (GATE || WS) __syncthreads();

    if (act) {
        #pragma unroll
        for (int mt = 0; mt < 5; ++mt)
            #pragma unroll
            for (int reg = 0; reg < 4; ++reg) {
                int gm = mt*16 + quad*4 + reg;
                if (gm < MR) {
                    int o = sgo + r16;
                    float v = acc[0][mt][reg] + bv;
                    if (GATE) {
                        float sg_ = 1.f/(1.f + __expf(-v));
                        if (o < HH)
                            sA[gm*SAS + XW + o] =
                                f2bf(sg_ * hload(&hL[gm*HSTR + o]));
                        else
                            ub[gm*UBS + (o - HH)] = f2bf(sg_);
                    } else {
                        float c  = 2.f/(1.f + __expf(-2.f*v)) - 1.f;
                        float u  = bf2f(ub[gm*UBS + o]);
                        float ho = hload(&hL[gm*HSTR + o]);
                        float hn = u*ho + (1.f - u)*c;
                        hstore(&hL[gm*HSTR + o], hn);
                        if (WS) sA[gm*SAS + o] = f2bf(hn);
                    }
                }
            }
    }
}

// ---------------------------------------------------------------------------
// Persistent kernel: 256 blocks x 1024 threads (16 waves, 4/SIMD).
// ---------------------------------------------------------------------------
__global__ __launch_bounds__(NT)
__attribute__((amdgpu_waves_per_eu(4, 4)))
void dcgru_persistent(
    const float* __restrict__ ihs,
    const float* __restrict__ bg0, const float* __restrict__ bc0,
    const float* __restrict__ bg1, const float* __restrict__ bc1,
    const float* __restrict__ Wp, const float* __restrict__ bp,
    float* __restrict__ out)
{
    extern __shared__ char smem[];
    unsigned short* h0  = (unsigned short*)(smem + OFF_H0);
    float*          h1  = (float*)(smem + OFF_H1);
    unsigned short* sA  = (unsigned short*)(smem + OFF_SA);
    unsigned short* ub  = (unsigned short*)(smem + OFF_UB);
    unsigned short* sbf = (unsigned short*)(smem + OFF_SBF);
    float*       xprev  = (float*)(smem + OFF_XP);

    const int tid  = threadIdx.x;
    const int lane = tid & 63;
    const int w    = tid >> 6;          /* 0..15 */
    const int bb   = blockIdx.x * NB;
    unsigned short* Ust = (unsigned short*)(smem + OFF_UST) + w*(16*UST_S);

    const unsigned short* BTg0 = g_wall + OFF_G0;
    const unsigned short* BTc0 = g_wall + OFF_C0;
    const unsigned short* BTg1 = g_wall + OFF_G1;
    const unsigned short* BTc1 = g_wall + OFF_C1;

    for (int i = tid; i < MR*HH; i += NT) {
        h0[i] = f2bf(ihs[(size_t)bb*2432 + i]);
        h1[(i >> 7)*H1S + (i & 127)] = ihs[(size_t)(BATCH + bb)*2432 + i];
    }
    for (int i = tid; i < MR; i += NT) xprev[i] = 0.f;
    /* zero sA fully (pad rows/cols stay zero) and Ust (stale reads finite) */
    for (int i = tid; i < 80*SAS/8; i += NT) ((bf16x8*)sA)[i] = (bf16x8)(short)0;
    for (int i = tid; i < 16*16*UST_S/8; i += NT)
        ((bf16x8*)(smem + OFF_UST))[i] = (bf16x8)(short)0;
    /* Tblk fragments -> LDS (18 KB, once) */
    for (int i = tid; i < 2*9*512/8; i += NT)
        ((bf16x8*)sbf)[i] = ((const bf16x8*)g_sbf)[i];
    const float wp0 = Wp[lane], wp1 = Wp[64 + lane], bpv = bp[0];
    __syncthreads();
    /* one-time: sA cols 0-127 <- h0 (persistent home; maintained by cand0) */
    for (int i = tid; i < MR*16; i += NT) {
        int row = i >> 4, ch = i & 15;
        *(bf16x8*)&sA[row*SAS + ch*8] = *(const bf16x8*)&h0[row*H0S + ch*8];
    }
    __syncthreads();

    for (int t = 0; t < SEQ; ++t) {
        // ---- layer 0 (K-loop over h only, x via rank-1; no staging) ----
        /* gate0: reads sA[0:128)=h0; r-epilogue -> sA[0:128), u -> ub */
        gconv_phase<4,256,true ,0,true ,false,unsigned short,H0S>(
            BTg0, bg0, h0, sA, ub, sbf, Ust, g_wx, xprev, lane, w);
        __syncthreads();
        /* cand0: reads sA[0:128)=r*h0; epilogue updates h0 AND restores
           sA[0:128)=h0new (persistent home) */
        gconv_phase<4,128,false,0,true ,true ,unsigned short,H0S>(
            BTc0, bc0, h0, sA, ub, sbf, Ust, g_wx + 3*256, xprev, lane, w);
        __syncthreads();

        // ---- stage layer 1: h1 half only (sA[0:128) already = h0) ----
        for (int i = tid; i < MR*16; i += NT) {
            int row = i >> 4, ch = i & 15;
            const float* hp = &h1[row*H1S + ch*8];
            f32x4 x0 = *(const f32x4*)hp;
            f32x4 x1 = *(const f32x4*)(hp + 4);
            bf16x8 v;
            v[0] = (short)f2bf(x0[0]); v[1] = (short)f2bf(x0[1]);
            v[2] = (short)f2bf(x0[2]); v[3] = (short)f2bf(x0[3]);
            v[4] = (short)f2bf(x1[0]); v[5] = (short)f2bf(x1[1]);
            v[6] = (short)f2bf(x1[2]); v[7] = (short)f2bf(x1[3]);
            *(bf16x8*)&sA[row*SAS + HH + ch*8] = v;
        }
        __syncthreads();
        /* gate1: reads [h0|h1]; r-epilogue -> sA[128:256), u -> ub */
        gconv_phase<8,256,true ,HH,false,false,float,H1S>(
            BTg1, bg1, h1, sA, ub, sbf, Ust, nullptr, xprev, lane, w);
        __syncthreads();
        /* cand1: reads [h0|r*h1]; updates h1 */
        gconv_phase<8,128,false,HH,false,false,float,H1S>(
            BTc1, bc1, h1, sA, ub, sbf, Ust, nullptr, xprev, lane, w);
        __syncthreads();

        // ---- projection: wave w -> batch w>>2, <=5 nodes each ----
        {
            int b  = w >> 2;
            int n0 = (w & 3) * 5;
            int n1 = n0 + 5; if (n1 > NN) n1 = NN;
            for (int n = n0; n < n1; ++n) {
                int row = b*NN + n;
                float s = h1[row*H1S + lane]*wp0 + h1[row*H1S + 64 + lane]*wp1;
                #pragma unroll
                for (int off = 32; off; off >>= 1) s += __shfl_down(s, off, 64);
                if (lane == 0) {
                    float v = s + bpv;
                    out[((size_t)t*BATCH + bb + b)*NN + n] = v;
                    xprev[row] = v;
                }
            }
        }
        __syncthreads();
    }
}

// ---------------------------------------------------------------------------
extern "C" void kernel_launch(void* const* d_in, const int* in_sizes, int n_in,
                              void* d_out, int out_size, void* d_ws, size_t ws_size,
                              hipStream_t stream) {
    const float* ihs = (const float*)d_in[1];
    const float* S   = (const float*)d_in[2];
    const float* Wg0 = (const float*)d_in[3];
    const float* bg0 = (const float*)d_in[4];
    const float* Wc0 = (const float*)d_in[5];
    const float* bc0 = (const float*)d_in[6];
    const float* Wg1 = (const float*)d_in[7];
    const float* bg1 = (const float*)d_in[8];
    const float* Wc1 = (const float*)d_in[9];
    const float* bc1 = (const float*)d_in[10];
    const float* Wp  = (const float*)d_in[11];
    const float* bp  = (const float*)d_in[12];
    float* out = (float*)d_out;

    sbf_kernel<<<1, 256, 0, stream>>>(S);
    wx_kernel<<<5, 256, 0, stream>>>(Wg0, Wc0);
    wconv_kernel<<<(3*256*128+255)/256, 256, 0, stream>>>(Wg0, 129, 256, 128, OFF_G0, 1);
    wconv_kernel<<<(3*128*128+255)/256, 256, 0, stream>>>(Wc0, 129, 128, 128, OFF_C0, 1);
    wconv_kernel<<<(3*256*256+255)/256, 256, 0, stream>>>(Wg1, 256, 256, 256, OFF_G1, 0);
    wconv_kernel<<<(3*128*256+255)/256, 256, 0, stream>>>(Wc1, 256, 128, 256, OFF_C1, 0);

    hipFuncSetAttribute((const void*)dcgru_persistent,
                        hipFuncAttributeMaxDynamicSharedMemorySize, LDS_BYTES);

    dcgru_persistent<<<NBLK, NT, LDS_BYTES, stream>>>(
        ihs, bg0, bc0, bg1, bc1, Wp, bp, out);
}

// Round 17
// 2358.014 us; speedup vs baseline: 1.2149x; 1.1879x over previous
//
#include <hip/hip_runtime.h>
#include <hip/hip_bf16.h>
#include <math.h>

#define SEQ   32
#define BATCH 1024
#define NN    19
#define HH    128
#define NB    4            /* batch elements per block */
#define MR    (NB*NN)      /* 76 rows per block */
#define SAS   264          /* sA row stride (bf16): 528 B = 16B-aligned, 4-bank shift */
#define H0S   128          /* h0 row stride (bf16) */
#define H1S   132          /* h1 row stride (f32): 528 B, 16B-aligned */
#define UBS   128          /* ub row stride (bf16) */
#define NBLK  (BATCH/NB)   /* 256 blocks, 1 per CU */
#define NT    1024         /* 16 waves, 4 per SIMD */
#define UST_S 40           /* Ust col stride (elems): 80 B = 16B-aligned, 20-bank shift */

#define OFF_G0 0
#define OFF_C0 122880
#define OFF_G1 184320
#define OFF_C1 380928
#define WTOT   479232      /* total weight elems (bf16) */

/* LDS map:
   h0   @      0  76*128*2 = 19456
   h1   @  19456  76*132*4 = 40128   (end  59584)
   sA   @  59584  80*264*2 = 42240   (end 101824; rows 76-79 stay zero)
   ub   @ 101824  76*128*2 = 19456   (end 121280)
   sbf  @ 121280  2*9*512*2= 18432   (end 139712; Tblk MFMA A-frags)
   Ust  @ 139712 16*16*40*2= 20480   (end 160192; per-wave mixing scratch)
   xp   @ 160192  76*4     =   304   (end 160496)  */
#define OFF_H0  0
#define OFF_H1  19456
#define OFF_SA  59584
#define OFF_UB  101824
#define OFF_SBF 121280
#define OFF_UST 139712
#define OFF_XP  160192
#define LDS_BYTES 160496

// Weights + Chebyshev block-diag fragments in device-global (L2-resident).
__device__ unsigned short g_wall[WTOT];
/* g_sbf: MFMA A-fragments of Tblk1 = blockdiag(S) (frags 0..8) and
   Tblk2 = blockdiag(2S^2-I) (frags 9..17), fragment-major [frag][lane][8],
   frag order grouped by kt: kt0:(mt 0,1,2) kt1:(mt 1,2,3,4) kt2:(mt 3,4). */
__device__ unsigned short g_sbf[2*9*512];

typedef __attribute__((ext_vector_type(8))) short  bf16x8;
typedef __attribute__((ext_vector_type(4))) short  bf16x4;
typedef __attribute__((ext_vector_type(4))) float  f32x4;

__device__ __forceinline__ unsigned short f2bf(float v) {
    __hip_bfloat16 b = __float2bfloat16(v);
    return *reinterpret_cast<unsigned short*>(&b);
}
__device__ __forceinline__ float bf2f(unsigned short u) {
    unsigned int x = ((unsigned int)u) << 16;
    return __uint_as_float(x);
}
__device__ __forceinline__ float hload(const unsigned short* p) { return bf2f(*p); }
__device__ __forceinline__ float hload(const float* p)          { return *p; }
__device__ __forceinline__ void  hstore(unsigned short* p, float v) { *p = f2bf(v); }
__device__ __forceinline__ void  hstore(float* p, float v)          { *p = v; }

// ---------------------------------------------------------------------------
// Setup 1: weight reorder/transpose into g_wall.
// Layer-0 (l0=1) K layout is [h(0..127) | x(128) | pad] so staging vectorizes.
// ---------------------------------------------------------------------------
__global__ __launch_bounds__(256) void wconv_kernel(
    const float* __restrict__ W, int F, int O, int KP, int off, int l0)
{
    int idx = blockIdx.x*256 + threadIdx.x;
    int total = 3*O*KP;
    if (idx >= total) return;
    int j   = idx / (O*KP);
    int r   = idx - j*(O*KP);
    int col = r / KP;
    int k   = r - col*KP;
    int src;
    if (l0) src = (k < HH) ? k+1 : ((k == HH) ? 0 : -1);
    else    src = (k < F) ? k : -1;
    float v = (src >= 0) ? W[(size_t)(j*F + src)*O + col] : 0.f;
    g_wall[off + idx] = f2bf(v);
}

// ---------------------------------------------------------------------------
// Setup 2: Tblk fragments (80x96 block-diag, zero-padded).
// A-frag layout (mfma_16x16x32): lane l, elem e ->
//   Tblk[fmt*16 + (l&15)][fkt*32 + (l>>4)*8 + e]
// ---------------------------------------------------------------------------
__global__ __launch_bounds__(256) void sbf_kernel(const float* __restrict__ S)
{
    __shared__ float sS[NN*NN], sS2[NN*NN];
    int tid = threadIdx.x;
    for (int i = tid; i < NN*NN; i += 256) sS[i] = S[i];
    __syncthreads();
    for (int i = tid; i < NN*NN; i += 256) {
        int m = i/NN, n = i - m*NN;
        float a = 0.f;
        for (int k = 0; k < NN; ++k) a += sS[m*NN+k]*sS[k*NN+n];
        sS2[i] = a;
    }
    __syncthreads();
    const int fmt[9] = {0,1,2, 1,2,3,4, 3,4};
    const int fkt[9] = {0,0,0, 1,1,1,1, 2,2};
    for (int idx = tid; idx < 2*9*512; idx += 256) {
        int mat = idx / 4608;
        int rem = idx - mat*4608;
        int i   = rem >> 9;
        int l   = (rem >> 3) & 63;
        int e   = rem & 7;
        int r   = fmt[i]*16 + (l & 15);
        int k   = fkt[i]*32 + (l >> 4)*8 + e;
        float v = 0.f;
        if (r < MR) {
            int b = r / NN, m = r - b*NN;
            int k0 = b*NN;
            if (k >= k0 && k < k0 + NN) {
                int n = k - k0;
                v = (mat == 0) ? sS[m*NN+n]
                               : (2.f*sS2[m*NN+n] - ((m==n)?1.f:0.f));
            }
        }
        g_sbf[idx] = f2bf(v);
    }
}

// ---------------------------------------------------------------------------
// One gconv phase, NTC=1 per wave (16 cols), flat fused structure (r5-proven):
//   acc[j] = X @ Wj  (fused 3-segment K-loop, depth-2 weight ring)
//   Y = acc[0] + Tblk1@acc[1] + Tblk2@acc[2] via per-wave Ust LDS scratch.
// GATE epilogue: r -> sA cols [XW,XW+128), u -> ub.  CAND: h update.
// ---------------------------------------------------------------------------
template<int KS, int OC, bool GATE, int XW, typename HT, int HSTR>
__device__ __forceinline__ void gconv_phase(
    const unsigned short* __restrict__ BT, const float* __restrict__ bias,
    HT* __restrict__ hL,
    unsigned short* __restrict__ sA, unsigned short* __restrict__ ub,
    const unsigned short* __restrict__ sbf, unsigned short* __restrict__ Ust,
    int lane, int w)
{
    constexpr int KP = KS*32;
    const int r16 = lane & 15, quad = lane >> 4;
    const int sgo = w*16;
    const bool act = (sgo < OC);     /* wave-uniform; inactive only for cand */

    constexpr int ktCnt[3]   = {3,4,2};
    constexpr int ktMT[3][4] = {{0,1,2,0},{1,2,3,4},{3,4,0,0}};
    constexpr int ktF0[3]    = {0,3,7};

    f32x4 acc[3][5];
    if (act) {
        const unsigned short* wb[3];
        #pragma unroll
        for (int j = 0; j < 3; ++j)
            wb[j] = BT + (size_t)(j*OC + sgo + r16)*KP + quad*8;

        #pragma unroll
        for (int j = 0; j < 3; ++j)
            #pragma unroll
            for (int mt = 0; mt < 5; ++mt) acc[j][mt] = (f32x4)0.f;

        /* fused K-loop, depth-2 weight ring (af read once per j-triple) */
        bf16x8 ring[2][3];
        #pragma unroll
        for (int j = 0; j < 3; ++j) {
            ring[0][j] = *(const bf16x8*)(wb[j]);
            if (KS > 1) ring[1][j] = *(const bf16x8*)(wb[j] + 32);
        }
        #pragma unroll
        for (int ks = 0; ks < KS; ++ks) {
            bf16x8 bcur[3];
            #pragma unroll
            for (int j = 0; j < 3; ++j) bcur[j] = ring[ks & 1][j];
            if (ks + 2 < KS) {
                #pragma unroll
                for (int j = 0; j < 3; ++j)
                    ring[ks & 1][j] = *(const bf16x8*)(wb[j] + (ks + 2)*32);
            }
            #pragma unroll
            for (int mt = 0; mt < 5; ++mt) {
                bf16x8 af = *(const bf16x8*)&sA[(mt*16 + r16)*SAS + ks*32 + quad*8];
                #pragma unroll
                for (int j = 0; j < 3; ++j)
                    acc[j][mt] = __builtin_amdgcn_mfma_f32_16x16x32_bf16(
                        af, bcur[j], acc[j][mt], 0, 0, 0);
            }
        }

        /* ---- output-side mixing: acc[0] += Tblk_jj @ acc[jj] ----
           Ust[col][r]: col = wave-local out col (r16), r = U row in the kt
           tile.  C-layout reg-quad is contiguous in r -> b64 writes.  Rows
           16..31 at kt=2 hold stale mt3 data (always finite, staged this
           same phase) multiplying zero Tblk cols -> no zero-fill needed. */
        #pragma unroll
        for (int jj = 1; jj <= 2; ++jj) {
            #pragma unroll
            for (int kt = 0; kt < 3; ++kt) {
                #pragma unroll
                for (int mtk = 0; mtk < 2; ++mtk) {
                    if (kt*2 + mtk < 5) {
                        bf16x4 pv;
                        pv[0] = (short)f2bf(acc[jj][kt*2+mtk][0]);
                        pv[1] = (short)f2bf(acc[jj][kt*2+mtk][1]);
                        pv[2] = (short)f2bf(acc[jj][kt*2+mtk][2]);
                        pv[3] = (short)f2bf(acc[jj][kt*2+mtk][3]);
                        *(bf16x4*)&Ust[r16*UST_S + mtk*16 + quad*4] = pv;
                    }
                }
                bf16x8 Bf = *(const bf16x8*)&Ust[r16*UST_S + quad*8];
                #pragma unroll
                for (int q = 0; q < ktCnt[kt]; ++q) {
                    const int mt = ktMT[kt][q];
                    bf16x8 af = *(const bf16x8*)
                        &sbf[((jj-1)*9 + ktF0[kt] + q)*512 + lane*8];
                    acc[0][mt] = __builtin_amdgcn_mfma_f32_16x16x32_bf16(
                        af, Bf, acc[0][mt], 0, 0, 0);
                }
            }
        }
    }

    float bv = act ? bias[sgo + r16] : 0.f;

    if (GATE) __syncthreads();   /* all sA reads done before epilogue rewrites */

    if (act) {
        #pragma unroll
        for (int mt = 0; mt < 5; ++mt)
            #pragma unroll
            for (int reg = 0; reg < 4; ++reg) {
                int gm = mt*16 + quad*4 + reg;
                if (gm < MR) {
                    int o = sgo + r16;
                    float v = acc[0][mt][reg] + bv;
                    if (GATE) {
                        float sg_ = 1.f/(1.f + __expf(-v));
                        if (o < HH)
                            sA[gm*SAS + XW + o] =
                                f2bf(sg_ * hload(&hL[gm*HSTR + o]));
                        else
                            ub[gm*UBS + (o - HH)] = f2bf(sg_);
                    } else {
                        float c  = 2.f/(1.f + __expf(-2.f*v)) - 1.f;
                        float u  = bf2f(ub[gm*UBS + o]);
                        float ho = hload(&hL[gm*HSTR + o]);
                        hstore(&hL[gm*HSTR + o], u*ho + (1.f - u)*c);
                    }
                }
            }
    }
}

// ---------------------------------------------------------------------------
// Persistent kernel: 256 blocks x 1024 threads (16 waves, 4/SIMD).
// amdgpu_waves_per_eu(4,4): exactly 4 waves/EU (LDS caps us there anyway).
// ---------------------------------------------------------------------------
__global__ __launch_bounds__(NT)
__attribute__((amdgpu_waves_per_eu(4, 4)))
void dcgru_persistent(
    const float* __restrict__ ihs,
    const float* __restrict__ bg0, const float* __restrict__ bc0,
    const float* __restrict__ bg1, const float* __restrict__ bc1,
    const float* __restrict__ Wp, const float* __restrict__ bp,
    float* __restrict__ out)
{
    extern __shared__ char smem[];
    unsigned short* h0  = (unsigned short*)(smem + OFF_H0);
    float*          h1  = (float*)(smem + OFF_H1);
    unsigned short* sA  = (unsigned short*)(smem + OFF_SA);
    unsigned short* ub  = (unsigned short*)(smem + OFF_UB);
    unsigned short* sbf = (unsigned short*)(smem + OFF_SBF);
    float*       xprev  = (float*)(smem + OFF_XP);

    const int tid  = threadIdx.x;
    const int lane = tid & 63;
    const int w    = tid >> 6;          /* 0..15 */
    const int bb   = blockIdx.x * NB;
    unsigned short* Ust = (unsigned short*)(smem + OFF_UST) + w*(16*UST_S);

    const unsigned short* BTg0 = g_wall + OFF_G0;
    const unsigned short* BTc0 = g_wall + OFF_C0;
    const unsigned short* BTg1 = g_wall + OFF_G1;
    const unsigned short* BTc1 = g_wall + OFF_C1;

    for (int i = tid; i < MR*HH; i += NT) {
        h0[i] = f2bf(ihs[(size_t)bb*2432 + i]);
        h1[(i >> 7)*H1S + (i & 127)] = ihs[(size_t)(BATCH + bb)*2432 + i];
    }
    for (int i = tid; i < MR; i += NT) xprev[i] = 0.f;
    /* zero sA fully (pad rows 76-79 + pad cols stay zero) and Ust (so any
       stale read is finite) */
    for (int i = tid; i < 80*SAS/8; i += NT) ((bf16x8*)sA)[i] = (bf16x8)(short)0;
    for (int i = tid; i < 16*16*UST_S/8; i += NT)
        ((bf16x8*)(smem + OFF_UST))[i] = (bf16x8)(short)0;
    /* Tblk fragments -> LDS (18 KB, once) */
    for (int i = tid; i < 2*9*512/8; i += NT)
        ((bf16x8*)sbf)[i] = ((const bf16x8*)g_sbf)[i];
    const float wp0 = Wp[lane], wp1 = Wp[64 + lane], bpv = bp[0];
    __syncthreads();

    for (int t = 0; t < SEQ; ++t) {
        // ---- stage layer 0: sA = [h0 | x | 0-pad]  (K = 160) ----
        for (int i = tid; i < MR*16; i += NT) {
            int row = i >> 4, ch = i & 15;
            *(bf16x8*)&sA[row*SAS + ch*8] =
                *(const bf16x8*)&h0[row*H0S + ch*8];
        }
        for (int i = tid; i < MR*4; i += NT) {
            int row = i >> 2, ch = i & 3;
            bf16x8 v = (bf16x8)(short)0;
            if (ch == 0) v[0] = (short)f2bf(xprev[row]);
            *(bf16x8*)&sA[row*SAS + HH + ch*8] = v;
        }
        __syncthreads();
        gconv_phase<5,256,true ,0,unsigned short,H0S>(BTg0, bg0, h0, sA, ub, sbf, Ust, lane, w);
        __syncthreads();
        /* sA now [r*h0 | x | 0] */
        gconv_phase<5,128,false,0,unsigned short,H0S>(BTc0, bc0, h0, sA, ub, sbf, Ust, lane, w);
        __syncthreads();

        // ---- stage layer 1: sA = [h0 | h1]  (K = 256) ----
        for (int i = tid; i < MR*16; i += NT) {
            int row = i >> 4, ch = i & 15;
            *(bf16x8*)&sA[row*SAS + ch*8] =
                *(const bf16x8*)&h0[row*H0S + ch*8];
        }
        for (int i = tid; i < MR*16; i += NT) {
            int row = i >> 4, ch = i & 15;
            const float* hp = &h1[row*H1S + ch*8];
            f32x4 x0 = *(const f32x4*)hp;
            f32x4 x1 = *(const f32x4*)(hp + 4);
            bf16x8 v;
            v[0] = (short)f2bf(x0[0]); v[1] = (short)f2bf(x0[1]);
            v[2] = (short)f2bf(x0[2]); v[3] = (short)f2bf(x0[3]);
            v[4] = (short)f2bf(x1[0]); v[5] = (short)f2bf(x1[1]);
            v[6] = (short)f2bf(x1[2]); v[7] = (short)f2bf(x1[3]);
            *(bf16x8*)&sA[row*SAS + HH + ch*8] = v;
        }
        __syncthreads();
        gconv_phase<8,256,true ,HH,float,H1S>(BTg1, bg1, h1, sA, ub, sbf, Ust, lane, w);
        __syncthreads();
        /* sA now [h0 | r*h1] */
        gconv_phase<8,128,false,HH,float,H1S>(BTc1, bc1, h1, sA, ub, sbf, Ust, lane, w);
        __syncthreads();

        // ---- projection: wave w -> batch w>>2, <=5 nodes each ----
        {
            int b  = w >> 2;
            int n0 = (w & 3) * 5;
            int n1 = n0 + 5; if (n1 > NN) n1 = NN;
            for (int n = n0; n < n1; ++n) {
                int row = b*NN + n;
                float s = h1[row*H1S + lane]*wp0 + h1[row*H1S + 64 + lane]*wp1;
                #pragma unroll
                for (int off = 32; off; off >>= 1) s += __shfl_down(s, off, 64);
                if (lane == 0) {
                    float v = s + bpv;
                    out[((size_t)t*BATCH + bb + b)*NN + n] = v;
                    xprev[row] = v;
                }
            }
        }
        __syncthreads();
    }
}

// ---------------------------------------------------------------------------
extern "C" void kernel_launch(void* const* d_in, const int* in_sizes, int n_in,
                              void* d_out, int out_size, void* d_ws, size_t ws_size,
                              hipStream_t stream) {
    const float* ihs = (const float*)d_in[1];
    const float* S   = (const float*)d_in[2];
    const float* Wg0 = (const float*)d_in[3];
    const float* bg0 = (const float*)d_in[4];
    const float* Wc0 = (const float*)d_in[5];
    const float* bc0 = (const float*)d_in[6];
    const float* Wg1 = (const float*)d_in[7];
    const float* bg1 = (const float*)d_in[8];
    const float* Wc1 = (const float*)d_in[9];
    const float* bc1 = (const float*)d_in[10];
    const float* Wp  = (const float*)d_in[11];
    const float* bp  = (const float*)d_in[12];
    float* out = (float*)d_out;

    sbf_kernel<<<1, 256, 0, stream>>>(S);
    wconv_kernel<<<(3*256*160+255)/256, 256, 0, stream>>>(Wg0, 129, 256, 160, OFF_G0, 1);
    wconv_kernel<<<(3*128*160+255)/256, 256, 0, stream>>>(Wc0, 129, 128, 160, OFF_C0, 1);
    wconv_kernel<<<(3*256*256+255)/256, 256, 0, stream>>>(Wg1, 256, 256, 256, OFF_G1, 0);
    wconv_kernel<<<(3*128*256+255)/256, 256, 0, stream>>>(Wc1, 256, 128, 256, OFF_C1, 0);

    hipFuncSetAttribute((const void*)dcgru_persistent,
                        hipFuncAttributeMaxDynamicSharedMemorySize, LDS_BYTES);

    dcgru_persistent<<<NBLK, NT, LDS_BYTES, stream>>>(
        ihs, bg0, bc0, bg1, bc1, Wp, bp, out);
}